// Round 3
// baseline (1124.240 us; speedup 1.0000x reference)
//
#include <hip/hip_runtime.h>
#include <math.h>

#define BB 32
#define NN 2048
#define DD 512
#define VV 32000
#define NSTEP 31

__device__ inline float sigm(float x){ return 1.0f/(1.0f+expf(-x)); }
__device__ inline float dot4(float4 a, float4 b){
  return a.x*b.x + a.y*b.y + a.z*b.z + a.w*b.w;
}

// Merged 8-way wave reduction: returns, in every lane, the full 64-lane sum
// of a_{lane&7}.
__device__ inline float red8(float a0,float a1,float a2,float a3,
                             float a4,float a5,float a6,float a7,int lane){
  float m01 = ((lane&1)? a1:a0) + __shfl_xor(((lane&1)? a0:a1),1,64);
  float m23 = ((lane&1)? a3:a2) + __shfl_xor(((lane&1)? a2:a3),1,64);
  float m45 = ((lane&1)? a5:a4) + __shfl_xor(((lane&1)? a4:a5),1,64);
  float m67 = ((lane&1)? a7:a6) + __shfl_xor(((lane&1)? a6:a7),1,64);
  float m03 = ((lane&2)? m23:m01) + __shfl_xor(((lane&2)? m01:m23),2,64);
  float m47 = ((lane&2)? m67:m45) + __shfl_xor(((lane&2)? m45:m67),2,64);
  float m   = ((lane&4)? m47:m03) + __shfl_xor(((lane&4)? m03:m47),4,64);
  m += __shfl_xor(m,8,64); m += __shfl_xor(m,16,64); m += __shfl_xor(m,32,64);
  return m;
}

// ---------------- counts, threshold; zero step-0 rows + sos one-hot --------
__global__ __launch_bounds__(256) void k_cnt(
    const int* __restrict__ pad, const int* __restrict__ pmask,
    const int* __restrict__ sosp,
    float* __restrict__ cntp, float* __restrict__ thr, float* __restrict__ out,
    unsigned int* __restrict__ flags) {
  __shared__ int r1[256], r2[256];
  int b = blockIdx.x, tid = threadIdx.x;
  if (b == 0 && tid < 256)
    __hip_atomic_store(&flags[tid], 0u, __ATOMIC_RELAXED,
                       __HIP_MEMORY_SCOPE_AGENT);
  float4* orow4 = (float4*)(out + (size_t)b*VV);
  float4 z = {0.f,0.f,0.f,0.f};
  for (int i = tid; i < VV/4; i += 256) orow4[i] = z;
  int cp = 0, cq = 0;
  for (int n = tid; n < NN; n += 256) { cp += pad[b*NN+n]; cq += pmask[b*NN+n]; }
  r1[tid] = cp; r2[tid] = cq; __syncthreads();
  for (int st = 128; st; st >>= 1) {
    if (tid < st) { r1[tid] += r1[tid+st]; r2[tid] += r2[tid+st]; }
    __syncthreads();
  }
  if (tid == 0) {
    cntp[b] = (float)r1[0];
    thr[b]  = 1.0f/(float)r2[0];
    out[(size_t)b*VV + sosp[0]] = 1.0f;
  }
}

// ---------------- h0 mean: partial sums (branch-free) ----------------------
__global__ __launch_bounds__(128) void k_meanpart(
    const float* __restrict__ enc, const int* __restrict__ pad,
    float* __restrict__ hpart) {
  int b = blockIdx.x, ch = blockIdx.y, kq = threadIdx.x;
  int n0 = ch*32;
  float4 acc = {0.f,0.f,0.f,0.f};
#pragma unroll 8
  for (int r = 0; r < 32; r++) {
    int n = n0 + r;
    float msk = (float)pad[b*NN + n];
    float4 v = *(const float4*)(enc + ((size_t)(b*NN + n))*DD + kq*4);
    acc.x += msk*v.x; acc.y += msk*v.y; acc.z += msk*v.z; acc.w += msk*v.w;
  }
  *(float4*)(hpart + ((size_t)(b*64 + ch))*DD + kq*4) = acc;
}

__global__ __launch_bounds__(128) void k_meanfin(
    const float* __restrict__ hpart, const float* __restrict__ cntp,
    float* __restrict__ h0, float* __restrict__ c) {
  int b = blockIdx.x, kq = threadIdx.x;
  float4 acc = {0.f,0.f,0.f,0.f};
  for (int ch = 0; ch < 64; ch++) {
    float4 v = *(const float4*)(hpart + ((size_t)(b*64 + ch))*DD + kq*4);
    acc.x += v.x; acc.y += v.y; acc.z += v.z; acc.w += v.w;
  }
  float ic = 1.0f/cntp[b];
  acc.x *= ic; acc.y *= ic; acc.z *= ic; acc.w *= ic;
  *(float4*)(h0 + b*DD + kq*4) = acc;
  *(float4*)(c  + b*DD + kq*4) = acc;
}

// ---------------- G0[m,r] = emb[tok_m].Wih[r] + bih[r]+bhh[r] --------------
__global__ __launch_bounds__(256) void k_g0(
    const float* __restrict__ emb, const float* __restrict__ Wih,
    const float* __restrict__ bih, const float* __restrict__ bhh,
    const int* __restrict__ target, const int* __restrict__ sosp,
    float* __restrict__ G0) {
  int nt = blockIdx.x, mg = blockIdx.y;
  int w = threadIdx.x>>6, lane = threadIdx.x&63;
  int m0 = mg*32 + w*8;
  float4 x0[8], x1[8];
#pragma unroll
  for (int j = 0; j < 8; j++) {
    int m = m0 + j, s = m >> 5, bb = m & 31;
    int tok = (s == 0) ? sosp[0] : target[s*BB + bb];
    const float* xp = emb + (size_t)tok*DD + lane*4;
    x0[j] = *(const float4*)xp;
    x1[j] = *(const float4*)(xp + 256);
  }
  int r0 = nt*32;
#pragma unroll 2
  for (int i = 0; i < 32; i++) {
    int r = r0 + i;
    const float* wp = Wih + (size_t)r*DD + lane*4;
    float4 w0 = *(const float4*)wp, w1 = *(const float4*)(wp + 256);
    float a0 = dot4(w0,x0[0]) + dot4(w1,x1[0]);
    float a1 = dot4(w0,x0[1]) + dot4(w1,x1[1]);
    float a2 = dot4(w0,x0[2]) + dot4(w1,x1[2]);
    float a3 = dot4(w0,x0[3]) + dot4(w1,x1[3]);
    float a4 = dot4(w0,x0[4]) + dot4(w1,x1[4]);
    float a5 = dot4(w0,x0[5]) + dot4(w1,x1[5]);
    float a6 = dot4(w0,x0[6]) + dot4(w1,x1[6]);
    float a7 = dot4(w0,x0[7]) + dot4(w1,x1[7]);
    float v = red8(a0,a1,a2,a3,a4,a5,a6,a7,lane) + bih[r] + bhh[r];
    if (lane < 8) G0[(size_t)(m0 + lane)*2048 + r] = v;
  }
}

// ---------------- fused 31-step LSTM recurrence (plain launch) -------------
// 256 blocks x 512 threads. 83 KB LDS forces exactly 1 block/CU, so all 256
// blocks are co-resident by construction (GPU is otherwise idle in stream
// order) -- no cooperative-launch API needed.
// Block bi owns d-cols {2bi,2bi+1}; its 8 Whh gate rows are PINNED in VGPRs
// across all 31 steps via an empty read-write asm (the asm is a potential
// writer, so the compiler cannot rematerialize them with reloads).
// Cross-block step barrier: per-block flag store (no RMW serialization) +
// each block's wave0 polls all 256 flags (4/lane); one acquire load
// (buffer_inv) before reading H[s]. h published via agent-scope relaxed
// atomic stores; __syncthreads' vmcnt(0) drain orders them before the flag.
__global__ __launch_bounds__(512, 2) void k_hloop(
    const float* __restrict__ h0, const float* __restrict__ Whh,
    const float* __restrict__ G0, float* __restrict__ H,
    unsigned int* __restrict__ flags) {
  __shared__ float pad[20736];   // 82.9 KB: occupancy limiter (1 block/CU)
  float* g = pad;                // only first 256 floats actually used
  int bi = blockIdx.x, d0 = bi*2;
  int tid = threadIdx.x;
  int w = tid>>6, lane = tid&63;
  float4 W0[8], W1[8];
#pragma unroll
  for (int j = 0; j < 8; j++) {
    int r = (j>>1)*DD + d0 + (j&1);
    const float* wp = Whh + (size_t)r*DD + lane*4;
    W0[j] = *(const float4*)wp; W1[j] = *(const float4*)(wp + 256);
  }
  int pb = tid>>1, pdd = tid&1;
  float creg = 0.f;
  if (tid < 64) creg = h0[pb*DD + d0 + pdd];

  for (int s = 0; s < NSTEP; s++) {
    // pin the Whh fragment in VGPRs for this iteration
#pragma unroll
    for (int j = 0; j < 8; j++) {
      asm volatile("" : "+v"(W0[j].x), "+v"(W0[j].y),
                        "+v"(W0[j].z), "+v"(W0[j].w),
                        "+v"(W1[j].x), "+v"(W1[j].y),
                        "+v"(W1[j].z), "+v"(W1[j].w));
    }
    const float* hin = (s == 0) ? h0 : (H + (size_t)(s-1)*BB*DD);
    // prefetch gate biases for this step (independent of h -> overlaps dots)
    float Gi = 0.f, Gf = 0.f, Gg = 0.f, Go = 0.f;
    if (tid < 64) {
      const float* G = G0 + ((size_t)s*BB + pb)*2048 + d0 + pdd;
      Gi = G[0]; Gf = G[512]; Gg = G[1024]; Go = G[1536];
    }
#pragma unroll
    for (int bb = 0; bb < 4; bb++) {
      int b = w*4 + bb;
      const float* hp = hin + b*DD + lane*4;
      float4 h0v = *(const float4*)hp, h1v = *(const float4*)(hp + 256);
      float a0 = dot4(h0v,W0[0]) + dot4(h1v,W1[0]);
      float a1 = dot4(h0v,W0[1]) + dot4(h1v,W1[1]);
      float a2 = dot4(h0v,W0[2]) + dot4(h1v,W1[2]);
      float a3 = dot4(h0v,W0[3]) + dot4(h1v,W1[3]);
      float a4 = dot4(h0v,W0[4]) + dot4(h1v,W1[4]);
      float a5 = dot4(h0v,W0[5]) + dot4(h1v,W1[5]);
      float a6 = dot4(h0v,W0[6]) + dot4(h1v,W1[6]);
      float a7 = dot4(h0v,W0[7]) + dot4(h1v,W1[7]);
      float v = red8(a0,a1,a2,a3,a4,a5,a6,a7,lane);
      if (lane < 8) g[b*8 + lane] = v;
    }
    __syncthreads();
    if (tid < 64) {
      float gi = g[pb*8 + 0 + pdd] + Gi;
      float gf = g[pb*8 + 2 + pdd] + Gf;
      float gg = g[pb*8 + 4 + pdd] + Gg;
      float go = g[pb*8 + 6 + pdd] + Go;
      creg = sigm(gf)*creg + sigm(gi)*tanhf(gg);
      float hn = sigm(go)*tanhf(creg);
      __hip_atomic_store(H + (size_t)s*BB*DD + pb*DD + d0 + pdd, hn,
                         __ATOMIC_RELAXED, __HIP_MEMORY_SCOPE_AGENT);
    }
    if (s == NSTEP-1) break;   // end-of-kernel flush publishes the last step
    __syncthreads();           // vmcnt(0) drain: h stores visible before flag
    if (tid == 0)
      __hip_atomic_store(&flags[bi], (unsigned)(s+1),
                         __ATOMIC_RELAXED, __HIP_MEMORY_SCOPE_AGENT);
    if (tid < 64) {
      unsigned tgt = (unsigned)(s+1);
      const unsigned int* fp = flags + tid*4;
      for (;;) {
        unsigned f0 = __hip_atomic_load(fp+0, __ATOMIC_RELAXED,
                                        __HIP_MEMORY_SCOPE_AGENT);
        unsigned f1 = __hip_atomic_load(fp+1, __ATOMIC_RELAXED,
                                        __HIP_MEMORY_SCOPE_AGENT);
        unsigned f2 = __hip_atomic_load(fp+2, __ATOMIC_RELAXED,
                                        __HIP_MEMORY_SCOPE_AGENT);
        unsigned f3 = __hip_atomic_load(fp+3, __ATOMIC_RELAXED,
                                        __HIP_MEMORY_SCOPE_AGENT);
        if (f0 >= tgt && f1 >= tgt && f2 >= tgt && f3 >= tgt) break;
        __builtin_amdgcn_s_sleep(1);
      }
    }
    __syncthreads();
    // acquire: one buffer_inv per wave so plain loads of H[s] are fresh
    unsigned acq = __hip_atomic_load(&flags[0], __ATOMIC_ACQUIRE,
                                     __HIP_MEMORY_SCOPE_AGENT);
    asm volatile("" :: "v"(acq));
  }
}

// ---------------- Q[m,r] = H[m].Watt[r], all steps -------------------------
__global__ __launch_bounds__(256) void k_qallw(
    const float* __restrict__ H, const float* __restrict__ Watt,
    float* __restrict__ Q) {
  int nt = blockIdx.x, mg = blockIdx.y;
  int w = threadIdx.x>>6, lane = threadIdx.x&63;
  int m0 = mg*32 + w*8;
  float4 x0[8], x1[8];
#pragma unroll
  for (int j = 0; j < 8; j++) {
    const float* xp = H + (size_t)(m0 + j)*DD + lane*4;
    x0[j] = *(const float4*)xp; x1[j] = *(const float4*)(xp + 256);
  }
  int r0 = nt*16;
#pragma unroll 2
  for (int i = 0; i < 16; i++) {
    int r = r0 + i;
    const float* wp = Watt + (size_t)r*DD + lane*4;
    float4 w0 = *(const float4*)wp, w1 = *(const float4*)(wp + 256);
    float a0 = dot4(w0,x0[0]) + dot4(w1,x1[0]);
    float a1 = dot4(w0,x0[1]) + dot4(w1,x1[1]);
    float a2 = dot4(w0,x0[2]) + dot4(w1,x1[2]);
    float a3 = dot4(w0,x0[3]) + dot4(w1,x1[3]);
    float a4 = dot4(w0,x0[4]) + dot4(w1,x1[4]);
    float a5 = dot4(w0,x0[5]) + dot4(w1,x1[5]);
    float a6 = dot4(w0,x0[6]) + dot4(w1,x1[6]);
    float a7 = dot4(w0,x0[7]) + dot4(w1,x1[7]);
    float v = red8(a0,a1,a2,a3,a4,a5,a6,a7,lane);
    if (lane < 8) Q[(size_t)(m0 + lane)*DD + r] = v;
  }
}

// ---------------- S[s,b,n] = enc[b,n,:].Q[s*32+b,:] ------------------------
__global__ __launch_bounds__(256) void k_scores3(
    const float* __restrict__ enc, const float* __restrict__ Q,
    float* __restrict__ S) {
  int nt = blockIdx.x, b = blockIdx.y;
  int w = threadIdx.x>>6, lane = threadIdx.x&63;
  int s0 = w*8;
  float4 q0[8], q1[8];
#pragma unroll
  for (int j = 0; j < 8; j++) {
    const float* qp = Q + (size_t)((s0 + j)*BB + b)*DD + lane*4;
    q0[j] = *(const float4*)qp; q1[j] = *(const float4*)(qp + 256);
  }
  int n0 = nt*32;
  int sl = s0 + (lane & 7);
#pragma unroll 2
  for (int i = 0; i < 32; i++) {
    int n = n0 + i;
    const float* ep = enc + ((size_t)(b*NN + n))*DD + lane*4;
    float4 e0 = *(const float4*)ep, e1 = *(const float4*)(ep + 256);
    float a0 = dot4(e0,q0[0]) + dot4(e1,q1[0]);
    float a1 = dot4(e0,q0[1]) + dot4(e1,q1[1]);
    float a2 = dot4(e0,q0[2]) + dot4(e1,q1[2]);
    float a3 = dot4(e0,q0[3]) + dot4(e1,q1[3]);
    float a4 = dot4(e0,q0[4]) + dot4(e1,q1[4]);
    float a5 = dot4(e0,q0[5]) + dot4(e1,q1[5]);
    float a6 = dot4(e0,q0[6]) + dot4(e1,q1[6]);
    float a7 = dot4(e0,q0[7]) + dot4(e1,q1[7]);
    float v = red8(a0,a1,a2,a3,a4,a5,a6,a7,lane);
    if (lane < 8 && sl < NSTEP) S[((size_t)sl*BB + b)*NN + n] = v;
  }
}

// ---------------- zero row + masked softmax + threshold + scatter + eos ----
__global__ __launch_bounds__(256) void k_scatter2(
    const float* __restrict__ S, const int* __restrict__ pmask,
    const int* __restrict__ tok, const float* __restrict__ thr,
    const int* __restrict__ eosp, float* __restrict__ out) {
  __shared__ float red[256];
  __shared__ float ex[NN];
  int s = blockIdx.x, b = blockIdx.y, tid = threadIdx.x;
  float* orow = out + ((size_t)(s+1)*BB + b)*VV;
  float4 z = {0.f,0.f,0.f,0.f};
  float4* orow4 = (float4*)orow;
  for (int i = tid; i < VV/4; i += 256) orow4[i] = z;
  const float* sr = S + ((size_t)s*BB + b)*NN;
  const int* pm = pmask + b*NN;
  float m = -3.4e38f;
  for (int n = tid; n < NN; n += 256) if (pm[n]) m = fmaxf(m, sr[n]);
  red[tid] = m; __syncthreads();
  for (int st = 128; st; st >>= 1) {
    if (tid < st) red[tid] = fmaxf(red[tid], red[tid+st]);
    __syncthreads();
  }
  float smax = red[0]; __syncthreads();
  float sum = 0.f;
  for (int n = tid; n < NN; n += 256) {
    float e = pm[n] ? expf(sr[n] - smax) : 0.f;
    ex[n] = e; sum += e;
  }
  red[tid] = sum; __syncthreads();
  for (int st = 128; st; st >>= 1) {
    if (tid < st) red[tid] += red[tid+st];
    __syncthreads();
  }
  float inv = 1.0f/red[0];
  float th = thr[b];
  float keep = 0.f;
  for (int n = tid; n < NN; n += 256) {
    float p = ex[n]*inv;
    if (p >= th) { atomicAdd(orow + tok[b*NN + n], p); keep += p; }
  }
  __syncthreads();
  red[tid] = keep; __syncthreads();
  for (int st = 128; st; st >>= 1) {
    if (tid < st) red[tid] += red[tid+st];
    __syncthreads();
  }
  if (tid == 0) orow[eosp[0]] = 1.0f - red[0];
}

extern "C" void kernel_launch(void* const* d_in, const int* in_sizes, int n_in,
                              void* d_out, int out_size, void* d_ws, size_t ws_size,
                              hipStream_t stream) {
  const float* enc   = (const float*)d_in[0];
  const float* emb   = (const float*)d_in[1];
  const float* Wih   = (const float*)d_in[2];
  const float* Whh   = (const float*)d_in[3];
  const float* bih   = (const float*)d_in[4];
  const float* bhh   = (const float*)d_in[5];
  const float* Watt  = (const float*)d_in[6];
  const int*   pad   = (const int*)d_in[7];
  const int*   pmask = (const int*)d_in[8];
  const int*   tok   = (const int*)d_in[9];
  const int*   target= (const int*)d_in[10];
  const int*   sosp  = (const int*)d_in[11];
  const int*   eosp  = (const int*)d_in[12];
  float* out = (float*)d_out;

  // workspace layout (floats), ~20.5 MB. hpart aliases G0 (used only before it).
  float* w    = (float*)d_ws;
  float* c    = w;                          // 32*512 (legacy; unused by hloop)
  float* h0   = c    + BB*DD;               // 32*512
  float* H    = h0   + BB*DD;               // 31*32*512
  float* Q    = H    + NSTEP*BB*DD;         // padded: 32*32*512
  float* S    = Q    + 32*BB*DD;            // 31*32*2048
  float* G0   = S    + (size_t)NSTEP*BB*NN; // 992*2048
  float* cntp = G0   + (size_t)992*2048;    // 32
  float* thr  = cntp + 32;                  // 32
  unsigned int* flags = (unsigned int*)(thr + 32); // 256 step flags
  float* hpart = G0;                        // 32*64*512 (alias, pre-G0 only)

  k_cnt<<<32, 256, 0, stream>>>(pad, pmask, sosp, cntp, thr, out, flags);
  k_meanpart<<<dim3(32,64), 128, 0, stream>>>(enc, pad, hpart);
  k_meanfin<<<32, 128, 0, stream>>>(hpart, cntp, h0, c);

  k_g0<<<dim3(64,31), 256, 0, stream>>>(emb, Wih, bih, bhh, target, sosp, G0);

  k_hloop<<<256, 512, 0, stream>>>(h0, Whh, G0, H, flags);

  k_qallw<<<dim3(32,31), 256, 0, stream>>>(H, Watt, Q);
  k_scores3<<<dim3(64,32), 256, 0, stream>>>(enc, Q, S);
  k_scatter2<<<dim3(NSTEP,32), 256, 0, stream>>>(S, pmask, tok, thr, eosp, out);
}

// Round 4
// 666.982 us; speedup vs baseline: 1.6856x; 1.6856x over previous
//
#include <hip/hip_runtime.h>
#include <math.h>

#define BB 32
#define NN 2048
#define DD 512
#define VV 32000
#define NSTEP 31

__device__ inline float sigm(float x){ return 1.0f/(1.0f+expf(-x)); }
__device__ inline float dot4(float4 a, float4 b){
  return a.x*b.x + a.y*b.y + a.z*b.z + a.w*b.w;
}

// Merged 8-way wave reduction: returns, in every lane, the full 64-lane sum
// of a_{lane&7}.
__device__ inline float red8(float a0,float a1,float a2,float a3,
                             float a4,float a5,float a6,float a7,int lane){
  float m01 = ((lane&1)? a1:a0) + __shfl_xor(((lane&1)? a0:a1),1,64);
  float m23 = ((lane&1)? a3:a2) + __shfl_xor(((lane&1)? a2:a3),1,64);
  float m45 = ((lane&1)? a5:a4) + __shfl_xor(((lane&1)? a4:a5),1,64);
  float m67 = ((lane&1)? a7:a6) + __shfl_xor(((lane&1)? a6:a7),1,64);
  float m03 = ((lane&2)? m23:m01) + __shfl_xor(((lane&2)? m01:m23),2,64);
  float m47 = ((lane&2)? m67:m45) + __shfl_xor(((lane&2)? m45:m67),2,64);
  float m   = ((lane&4)? m47:m03) + __shfl_xor(((lane&4)? m03:m47),4,64);
  m += __shfl_xor(m,8,64); m += __shfl_xor(m,16,64); m += __shfl_xor(m,32,64);
  return m;
}

// ---------------- counts, threshold; zero step-0 rows + sos one-hot --------
__global__ __launch_bounds__(256) void k_cnt(
    const int* __restrict__ pad, const int* __restrict__ pmask,
    const int* __restrict__ sosp,
    float* __restrict__ cntp, float* __restrict__ thr, float* __restrict__ out,
    unsigned int* __restrict__ flags) {
  __shared__ int r1[256], r2[256];
  int b = blockIdx.x, tid = threadIdx.x;
  if (b == 0 && tid <= 256)   // 256 arrival flags + release word (flags[256])
    __hip_atomic_store(&flags[tid], 0u, __ATOMIC_RELAXED,
                       __HIP_MEMORY_SCOPE_AGENT);
  float4* orow4 = (float4*)(out + (size_t)b*VV);
  float4 z = {0.f,0.f,0.f,0.f};
  for (int i = tid; i < VV/4; i += 256) orow4[i] = z;
  int cp = 0, cq = 0;
  for (int n = tid; n < NN; n += 256) { cp += pad[b*NN+n]; cq += pmask[b*NN+n]; }
  r1[tid] = cp; r2[tid] = cq; __syncthreads();
  for (int st = 128; st; st >>= 1) {
    if (tid < st) { r1[tid] += r1[tid+st]; r2[tid] += r2[tid+st]; }
    __syncthreads();
  }
  if (tid == 0) {
    cntp[b] = (float)r1[0];
    thr[b]  = 1.0f/(float)r2[0];
    out[(size_t)b*VV + sosp[0]] = 1.0f;
  }
}

// ---------------- h0 mean: partial sums (branch-free) ----------------------
__global__ __launch_bounds__(128) void k_meanpart(
    const float* __restrict__ enc, const int* __restrict__ pad,
    float* __restrict__ hpart) {
  int b = blockIdx.x, ch = blockIdx.y, kq = threadIdx.x;
  int n0 = ch*32;
  float4 acc = {0.f,0.f,0.f,0.f};
#pragma unroll 8
  for (int r = 0; r < 32; r++) {
    int n = n0 + r;
    float msk = (float)pad[b*NN + n];
    float4 v = *(const float4*)(enc + ((size_t)(b*NN + n))*DD + kq*4);
    acc.x += msk*v.x; acc.y += msk*v.y; acc.z += msk*v.z; acc.w += msk*v.w;
  }
  *(float4*)(hpart + ((size_t)(b*64 + ch))*DD + kq*4) = acc;
}

__global__ __launch_bounds__(128) void k_meanfin(
    const float* __restrict__ hpart, const float* __restrict__ cntp,
    float* __restrict__ h0, float* __restrict__ c) {
  int b = blockIdx.x, kq = threadIdx.x;
  float4 acc = {0.f,0.f,0.f,0.f};
  for (int ch = 0; ch < 64; ch++) {
    float4 v = *(const float4*)(hpart + ((size_t)(b*64 + ch))*DD + kq*4);
    acc.x += v.x; acc.y += v.y; acc.z += v.z; acc.w += v.w;
  }
  float ic = 1.0f/cntp[b];
  acc.x *= ic; acc.y *= ic; acc.z *= ic; acc.w *= ic;
  *(float4*)(h0 + b*DD + kq*4) = acc;
  *(float4*)(c  + b*DD + kq*4) = acc;
}

// ---------------- G0[m,r] = emb[tok_m].Wih[r] + bih[r]+bhh[r] --------------
__global__ __launch_bounds__(256) void k_g0(
    const float* __restrict__ emb, const float* __restrict__ Wih,
    const float* __restrict__ bih, const float* __restrict__ bhh,
    const int* __restrict__ target, const int* __restrict__ sosp,
    float* __restrict__ G0) {
  int nt = blockIdx.x, mg = blockIdx.y;
  int w = threadIdx.x>>6, lane = threadIdx.x&63;
  int m0 = mg*32 + w*8;
  float4 x0[8], x1[8];
#pragma unroll
  for (int j = 0; j < 8; j++) {
    int m = m0 + j, s = m >> 5, bb = m & 31;
    int tok = (s == 0) ? sosp[0] : target[s*BB + bb];
    const float* xp = emb + (size_t)tok*DD + lane*4;
    x0[j] = *(const float4*)xp;
    x1[j] = *(const float4*)(xp + 256);
  }
  int r0 = nt*32;
#pragma unroll 2
  for (int i = 0; i < 32; i++) {
    int r = r0 + i;
    const float* wp = Wih + (size_t)r*DD + lane*4;
    float4 w0 = *(const float4*)wp, w1 = *(const float4*)(wp + 256);
    float a0 = dot4(w0,x0[0]) + dot4(w1,x1[0]);
    float a1 = dot4(w0,x0[1]) + dot4(w1,x1[1]);
    float a2 = dot4(w0,x0[2]) + dot4(w1,x1[2]);
    float a3 = dot4(w0,x0[3]) + dot4(w1,x1[3]);
    float a4 = dot4(w0,x0[4]) + dot4(w1,x1[4]);
    float a5 = dot4(w0,x0[5]) + dot4(w1,x1[5]);
    float a6 = dot4(w0,x0[6]) + dot4(w1,x1[6]);
    float a7 = dot4(w0,x0[7]) + dot4(w1,x1[7]);
    float v = red8(a0,a1,a2,a3,a4,a5,a6,a7,lane) + bih[r] + bhh[r];
    if (lane < 8) G0[(size_t)(m0 + lane)*2048 + r] = v;
  }
}

// ---------------- fused 31-step LSTM recurrence (plain launch) -------------
// 256 blocks x 512 threads; 83 KB LDS forces 1 block/CU so all 256 blocks
// are co-resident by construction. Block bi owns d-cols {2bi,2bi+1}; its 8
// Whh gate rows are PINNED in VGPRs across all 31 steps (asm read-write pin,
// round-3-verified: VGPR 88, weights never reloaded).
//
// Step barrier, v3 (fixes round-2 arrival serialization AND round-3 poll
// storm):
//   arrival: per-block flag STORE (parallel, no RMW).
//   gather:  ONLY block 0's wave 0 reads the 256 flags (4/lane); when its
//            wave reconverges, lane 0 stores a single release word = s+1.
//   wait:    every block's tid0 polls THE ONE release word (pure loads,
//            single address -- the pattern that was cheap in round 2).
//   acquire: one agent-scope acquire load (buffer_inv) before reading H[s].
// h is published via agent-scope relaxed atomic stores; __syncthreads'
// vmcnt(0) drain orders them before the flag store (round-2/3-verified).
__global__ __launch_bounds__(512, 2) void k_hloop(
    const float* __restrict__ h0, const float* __restrict__ Whh,
    const float* __restrict__ G0, float* __restrict__ H,
    unsigned int* __restrict__ flags) {
  __shared__ float pad[20736];   // 82.9 KB: occupancy limiter (1 block/CU)
  float* g = pad;                // only first 256 floats actually used
  int bi = blockIdx.x, d0 = bi*2;
  int tid = threadIdx.x;
  int w = tid>>6, lane = tid&63;
  float4 W0[8], W1[8];
#pragma unroll
  for (int j = 0; j < 8; j++) {
    int r = (j>>1)*DD + d0 + (j&1);
    const float* wp = Whh + (size_t)r*DD + lane*4;
    W0[j] = *(const float4*)wp; W1[j] = *(const float4*)(wp + 256);
  }
  int pb = tid>>1, pdd = tid&1;
  float creg = 0.f;
  if (tid < 64) creg = h0[pb*DD + d0 + pdd];

  for (int s = 0; s < NSTEP; s++) {
    // pin the Whh fragment in VGPRs for this iteration
#pragma unroll
    for (int j = 0; j < 8; j++) {
      asm volatile("" : "+v"(W0[j].x), "+v"(W0[j].y),
                        "+v"(W0[j].z), "+v"(W0[j].w),
                        "+v"(W1[j].x), "+v"(W1[j].y),
                        "+v"(W1[j].z), "+v"(W1[j].w));
    }
    const float* hin = (s == 0) ? h0 : (H + (size_t)(s-1)*BB*DD);
    // prefetch gate biases for this step (independent of h -> overlaps dots)
    float Gi = 0.f, Gf = 0.f, Gg = 0.f, Go = 0.f;
    if (tid < 64) {
      const float* G = G0 + ((size_t)s*BB + pb)*2048 + d0 + pdd;
      Gi = G[0]; Gf = G[512]; Gg = G[1024]; Go = G[1536];
    }
#pragma unroll
    for (int bb = 0; bb < 4; bb++) {
      int b = w*4 + bb;
      const float* hp = hin + b*DD + lane*4;
      float4 h0v = *(const float4*)hp, h1v = *(const float4*)(hp + 256);
      float a0 = dot4(h0v,W0[0]) + dot4(h1v,W1[0]);
      float a1 = dot4(h0v,W0[1]) + dot4(h1v,W1[1]);
      float a2 = dot4(h0v,W0[2]) + dot4(h1v,W1[2]);
      float a3 = dot4(h0v,W0[3]) + dot4(h1v,W1[3]);
      float a4 = dot4(h0v,W0[4]) + dot4(h1v,W1[4]);
      float a5 = dot4(h0v,W0[5]) + dot4(h1v,W1[5]);
      float a6 = dot4(h0v,W0[6]) + dot4(h1v,W1[6]);
      float a7 = dot4(h0v,W0[7]) + dot4(h1v,W1[7]);
      float v = red8(a0,a1,a2,a3,a4,a5,a6,a7,lane);
      if (lane < 8) g[b*8 + lane] = v;
    }
    __syncthreads();
    if (tid < 64) {
      float gi = g[pb*8 + 0 + pdd] + Gi;
      float gf = g[pb*8 + 2 + pdd] + Gf;
      float gg = g[pb*8 + 4 + pdd] + Gg;
      float go = g[pb*8 + 6 + pdd] + Go;
      creg = sigm(gf)*creg + sigm(gi)*tanhf(gg);
      float hn = sigm(go)*tanhf(creg);
      __hip_atomic_store(H + (size_t)s*BB*DD + pb*DD + d0 + pdd, hn,
                         __ATOMIC_RELAXED, __HIP_MEMORY_SCOPE_AGENT);
    }
    if (s == NSTEP-1) break;   // end-of-kernel flush publishes the last step
    __syncthreads();           // vmcnt(0) drain: h stores visible before flag
    unsigned tgt = (unsigned)(s+1);
    if (tid == 0)
      __hip_atomic_store(&flags[bi], tgt,
                         __ATOMIC_RELAXED, __HIP_MEMORY_SCOPE_AGENT);
    if (bi == 0 && tid < 64) {
      // gatherer wave: poll 4 flags/lane; wave reconverges when ALL lanes done
      const unsigned int* fp = flags + tid*4;
      for (;;) {
        unsigned f0 = __hip_atomic_load(fp+0, __ATOMIC_RELAXED,
                                        __HIP_MEMORY_SCOPE_AGENT);
        unsigned f1 = __hip_atomic_load(fp+1, __ATOMIC_RELAXED,
                                        __HIP_MEMORY_SCOPE_AGENT);
        unsigned f2 = __hip_atomic_load(fp+2, __ATOMIC_RELAXED,
                                        __HIP_MEMORY_SCOPE_AGENT);
        unsigned f3 = __hip_atomic_load(fp+3, __ATOMIC_RELAXED,
                                        __HIP_MEMORY_SCOPE_AGENT);
        if (f0 >= tgt && f1 >= tgt && f2 >= tgt && f3 >= tgt) break;
        __builtin_amdgcn_s_sleep(1);
      }
      if (tid == 0)
        __hip_atomic_store(&flags[256], tgt,
                           __ATOMIC_RELAXED, __HIP_MEMORY_SCOPE_AGENT);
    }
    if (tid == 0) {
      // single-address release poll (pure loads -- cheap, round-2-verified)
      while (__hip_atomic_load(&flags[256], __ATOMIC_RELAXED,
                               __HIP_MEMORY_SCOPE_AGENT) < tgt)
        __builtin_amdgcn_s_sleep(1);
    }
    __syncthreads();
    // acquire: one buffer_inv per block so plain loads of H[s] are fresh
    if (tid == 0) {
      unsigned acq = __hip_atomic_load(&flags[256], __ATOMIC_ACQUIRE,
                                       __HIP_MEMORY_SCOPE_AGENT);
      asm volatile("" :: "v"(acq));
    }
    __syncthreads();
  }
}

// ---------------- Q[m,r] = H[m].Watt[r], all steps -------------------------
__global__ __launch_bounds__(256) void k_qallw(
    const float* __restrict__ H, const float* __restrict__ Watt,
    float* __restrict__ Q) {
  int nt = blockIdx.x, mg = blockIdx.y;
  int w = threadIdx.x>>6, lane = threadIdx.x&63;
  int m0 = mg*32 + w*8;
  float4 x0[8], x1[8];
#pragma unroll
  for (int j = 0; j < 8; j++) {
    const float* xp = H + (size_t)(m0 + j)*DD + lane*4;
    x0[j] = *(const float4*)xp; x1[j] = *(const float4*)(xp + 256);
  }
  int r0 = nt*16;
#pragma unroll 2
  for (int i = 0; i < 16; i++) {
    int r = r0 + i;
    const float* wp = Watt + (size_t)r*DD + lane*4;
    float4 w0 = *(const float4*)wp, w1 = *(const float4*)(wp + 256);
    float a0 = dot4(w0,x0[0]) + dot4(w1,x1[0]);
    float a1 = dot4(w0,x0[1]) + dot4(w1,x1[1]);
    float a2 = dot4(w0,x0[2]) + dot4(w1,x1[2]);
    float a3 = dot4(w0,x0[3]) + dot4(w1,x1[3]);
    float a4 = dot4(w0,x0[4]) + dot4(w1,x1[4]);
    float a5 = dot4(w0,x0[5]) + dot4(w1,x1[5]);
    float a6 = dot4(w0,x0[6]) + dot4(w1,x1[6]);
    float a7 = dot4(w0,x0[7]) + dot4(w1,x1[7]);
    float v = red8(a0,a1,a2,a3,a4,a5,a6,a7,lane);
    if (lane < 8) Q[(size_t)(m0 + lane)*DD + r] = v;
  }
}

// ---------------- S[s,b,n] = enc[b,n,:].Q[s*32+b,:] ------------------------
__global__ __launch_bounds__(256) void k_scores3(
    const float* __restrict__ enc, const float* __restrict__ Q,
    float* __restrict__ S) {
  int nt = blockIdx.x, b = blockIdx.y;
  int w = threadIdx.x>>6, lane = threadIdx.x&63;
  int s0 = w*8;
  float4 q0[8], q1[8];
#pragma unroll
  for (int j = 0; j < 8; j++) {
    const float* qp = Q + (size_t)((s0 + j)*BB + b)*DD + lane*4;
    q0[j] = *(const float4*)qp; q1[j] = *(const float4*)(qp + 256);
  }
  int n0 = nt*32;
  int sl = s0 + (lane & 7);
#pragma unroll 2
  for (int i = 0; i < 32; i++) {
    int n = n0 + i;
    const float* ep = enc + ((size_t)(b*NN + n))*DD + lane*4;
    float4 e0 = *(const float4*)ep, e1 = *(const float4*)(ep + 256);
    float a0 = dot4(e0,q0[0]) + dot4(e1,q1[0]);
    float a1 = dot4(e0,q0[1]) + dot4(e1,q1[1]);
    float a2 = dot4(e0,q0[2]) + dot4(e1,q1[2]);
    float a3 = dot4(e0,q0[3]) + dot4(e1,q1[3]);
    float a4 = dot4(e0,q0[4]) + dot4(e1,q1[4]);
    float a5 = dot4(e0,q0[5]) + dot4(e1,q1[5]);
    float a6 = dot4(e0,q0[6]) + dot4(e1,q1[6]);
    float a7 = dot4(e0,q0[7]) + dot4(e1,q1[7]);
    float v = red8(a0,a1,a2,a3,a4,a5,a6,a7,lane);
    if (lane < 8 && sl < NSTEP) S[((size_t)sl*BB + b)*NN + n] = v;
  }
}

// ---------------- zero row + masked softmax + threshold + scatter + eos ----
__global__ __launch_bounds__(256) void k_scatter2(
    const float* __restrict__ S, const int* __restrict__ pmask,
    const int* __restrict__ tok, const float* __restrict__ thr,
    const int* __restrict__ eosp, float* __restrict__ out) {
  __shared__ float red[256];
  __shared__ float ex[NN];
  int s = blockIdx.x, b = blockIdx.y, tid = threadIdx.x;
  float* orow = out + ((size_t)(s+1)*BB + b)*VV;
  float4 z = {0.f,0.f,0.f,0.f};
  float4* orow4 = (float4*)orow;
  for (int i = tid; i < VV/4; i += 256) orow4[i] = z;
  const float* sr = S + ((size_t)s*BB + b)*NN;
  const int* pm = pmask + b*NN;
  float m = -3.4e38f;
  for (int n = tid; n < NN; n += 256) if (pm[n]) m = fmaxf(m, sr[n]);
  red[tid] = m; __syncthreads();
  for (int st = 128; st; st >>= 1) {
    if (tid < st) red[tid] = fmaxf(red[tid], red[tid+st]);
    __syncthreads();
  }
  float smax = red[0]; __syncthreads();
  float sum = 0.f;
  for (int n = tid; n < NN; n += 256) {
    float e = pm[n] ? expf(sr[n] - smax) : 0.f;
    ex[n] = e; sum += e;
  }
  red[tid] = sum; __syncthreads();
  for (int st = 128; st; st >>= 1) {
    if (tid < st) red[tid] += red[tid+st];
    __syncthreads();
  }
  float inv = 1.0f/red[0];
  float th = thr[b];
  float keep = 0.f;
  for (int n = tid; n < NN; n += 256) {
    float p = ex[n]*inv;
    if (p >= th) { atomicAdd(orow + tok[b*NN + n], p); keep += p; }
  }
  __syncthreads();
  red[tid] = keep; __syncthreads();
  for (int st = 128; st; st >>= 1) {
    if (tid < st) red[tid] += red[tid+st];
    __syncthreads();
  }
  if (tid == 0) orow[eosp[0]] = 1.0f - red[0];
}

extern "C" void kernel_launch(void* const* d_in, const int* in_sizes, int n_in,
                              void* d_out, int out_size, void* d_ws, size_t ws_size,
                              hipStream_t stream) {
  const float* enc   = (const float*)d_in[0];
  const float* emb   = (const float*)d_in[1];
  const float* Wih   = (const float*)d_in[2];
  const float* Whh   = (const float*)d_in[3];
  const float* bih   = (const float*)d_in[4];
  const float* bhh   = (const float*)d_in[5];
  const float* Watt  = (const float*)d_in[6];
  const int*   pad   = (const int*)d_in[7];
  const int*   pmask = (const int*)d_in[8];
  const int*   tok   = (const int*)d_in[9];
  const int*   target= (const int*)d_in[10];
  const int*   sosp  = (const int*)d_in[11];
  const int*   eosp  = (const int*)d_in[12];
  float* out = (float*)d_out;

  // workspace layout (floats), ~20.5 MB. hpart aliases G0 (used only before it).
  float* w    = (float*)d_ws;
  float* c    = w;                          // 32*512 (legacy; unused by hloop)
  float* h0   = c    + BB*DD;               // 32*512
  float* H    = h0   + BB*DD;               // 31*32*512
  float* Q    = H    + NSTEP*BB*DD;         // padded: 32*32*512
  float* S    = Q    + 32*BB*DD;            // 31*32*2048
  float* G0   = S    + (size_t)NSTEP*BB*NN; // 992*2048
  float* cntp = G0   + (size_t)992*2048;    // 32
  float* thr  = cntp + 32;                  // 32
  unsigned int* flags = (unsigned int*)(thr + 32); // 256 flags + release word
  float* hpart = G0;                        // 32*64*512 (alias, pre-G0 only)

  k_cnt<<<32, 256, 0, stream>>>(pad, pmask, sosp, cntp, thr, out, flags);
  k_meanpart<<<dim3(32,64), 128, 0, stream>>>(enc, pad, hpart);
  k_meanfin<<<32, 128, 0, stream>>>(hpart, cntp, h0, c);

  k_g0<<<dim3(64,31), 256, 0, stream>>>(emb, Wih, bih, bhh, target, sosp, G0);

  k_hloop<<<256, 512, 0, stream>>>(h0, Whh, G0, H, flags);

  k_qallw<<<dim3(32,31), 256, 0, stream>>>(H, Watt, Q);
  k_scores3<<<dim3(64,32), 256, 0, stream>>>(enc, Q, S);
  k_scatter2<<<dim3(NSTEP,32), 256, 0, stream>>>(S, pmask, tok, thr, eosp, out);
}

// Round 5
// 602.517 us; speedup vs baseline: 1.8659x; 1.1070x over previous
//
#include <hip/hip_runtime.h>
#include <math.h>

#define BB 32
#define NN 2048
#define DD 512
#define VV 32000
#define NSTEP 31

__device__ inline float sigm(float x){ return 1.0f/(1.0f+expf(-x)); }
__device__ inline float dot4(float4 a, float4 b){
  return a.x*b.x + a.y*b.y + a.z*b.z + a.w*b.w;
}

// Merged 8-way wave reduction: returns, in every lane, the full 64-lane sum
// of a_{lane&7}.
__device__ inline float red8(float a0,float a1,float a2,float a3,
                             float a4,float a5,float a6,float a7,int lane){
  float m01 = ((lane&1)? a1:a0) + __shfl_xor(((lane&1)? a0:a1),1,64);
  float m23 = ((lane&1)? a3:a2) + __shfl_xor(((lane&1)? a2:a3),1,64);
  float m45 = ((lane&1)? a5:a4) + __shfl_xor(((lane&1)? a4:a5),1,64);
  float m67 = ((lane&1)? a7:a6) + __shfl_xor(((lane&1)? a6:a7),1,64);
  float m03 = ((lane&2)? m23:m01) + __shfl_xor(((lane&2)? m01:m23),2,64);
  float m47 = ((lane&2)? m67:m45) + __shfl_xor(((lane&2)? m45:m67),2,64);
  float m   = ((lane&4)? m47:m03) + __shfl_xor(((lane&4)? m03:m47),4,64);
  m += __shfl_xor(m,8,64); m += __shfl_xor(m,16,64); m += __shfl_xor(m,32,64);
  return m;
}

// ---------------- counts, threshold; zero step-0 rows + sos one-hot --------
__global__ __launch_bounds__(256) void k_cnt(
    const int* __restrict__ pad, const int* __restrict__ pmask,
    const int* __restrict__ sosp,
    float* __restrict__ cntp, float* __restrict__ thr, float* __restrict__ out,
    unsigned int* __restrict__ flags) {
  __shared__ int r1[256], r2[256];
  int b = blockIdx.x, tid = threadIdx.x;
  if (b == 0) {                       // 256 arrival flags + release word
    if (tid < 256)
      __hip_atomic_store(&flags[tid], 0u, __ATOMIC_RELAXED,
                         __HIP_MEMORY_SCOPE_AGENT);
    if (tid == 0)
      __hip_atomic_store(&flags[256], 0u, __ATOMIC_RELAXED,
                         __HIP_MEMORY_SCOPE_AGENT);
  }
  float4* orow4 = (float4*)(out + (size_t)b*VV);
  float4 z = {0.f,0.f,0.f,0.f};
  for (int i = tid; i < VV/4; i += 256) orow4[i] = z;
  int cp = 0, cq = 0;
  for (int n = tid; n < NN; n += 256) { cp += pad[b*NN+n]; cq += pmask[b*NN+n]; }
  r1[tid] = cp; r2[tid] = cq; __syncthreads();
  for (int st = 128; st; st >>= 1) {
    if (tid < st) { r1[tid] += r1[tid+st]; r2[tid] += r2[tid+st]; }
    __syncthreads();
  }
  if (tid == 0) {
    cntp[b] = (float)r1[0];
    thr[b]  = 1.0f/(float)r2[0];
    out[(size_t)b*VV + sosp[0]] = 1.0f;
  }
}

// ---------------- h0 mean: partial sums (branch-free) ----------------------
__global__ __launch_bounds__(128) void k_meanpart(
    const float* __restrict__ enc, const int* __restrict__ pad,
    float* __restrict__ hpart) {
  int b = blockIdx.x, ch = blockIdx.y, kq = threadIdx.x;
  int n0 = ch*32;
  float4 acc = {0.f,0.f,0.f,0.f};
#pragma unroll 8
  for (int r = 0; r < 32; r++) {
    int n = n0 + r;
    float msk = (float)pad[b*NN + n];
    float4 v = *(const float4*)(enc + ((size_t)(b*NN + n))*DD + kq*4);
    acc.x += msk*v.x; acc.y += msk*v.y; acc.z += msk*v.z; acc.w += msk*v.w;
  }
  *(float4*)(hpart + ((size_t)(b*64 + ch))*DD + kq*4) = acc;
}

__global__ __launch_bounds__(128) void k_meanfin(
    const float* __restrict__ hpart, const float* __restrict__ cntp,
    float* __restrict__ h0, float* __restrict__ c) {
  int b = blockIdx.x, kq = threadIdx.x;
  float4 acc = {0.f,0.f,0.f,0.f};
  for (int ch = 0; ch < 64; ch++) {
    float4 v = *(const float4*)(hpart + ((size_t)(b*64 + ch))*DD + kq*4);
    acc.x += v.x; acc.y += v.y; acc.z += v.z; acc.w += v.w;
  }
  float ic = 1.0f/cntp[b];
  acc.x *= ic; acc.y *= ic; acc.z *= ic; acc.w *= ic;
  *(float4*)(h0 + b*DD + kq*4) = acc;
  *(float4*)(c  + b*DD + kq*4) = acc;
}

// ---------------- fused 31-step LSTM recurrence + G0 pipeline --------------
// 256 blocks x 512 threads; 83 KB LDS forces 1 block/CU (co-residency by
// construction). Block bi owns d-cols {2bi,2bi+1}: 8 Whh rows AND 8 Wih rows
// pinned in VGPRs across all steps (asm read-write pin).
//
// G0 fusion: the input-side gate slice G[s+1] (= emb[tok_{s+1,b}].Wih[r] +
// biases, same dot structure as the h-dots) is computed BETWEEN the arrival
// flag store and the release poll, into a 2-slot LDS buffer -- its ~1.4 us of
// VALU work hides the barrier gather/release latency, and G never touches
// global memory (k_g0 kernel deleted).
//
// Barrier (v4): arrival = per-block flag store; gather = block 0 wave 0
// reads 256 flags (4/lane); release = single word; wait = single-address
// relaxed poll. NO acquire/buffer_inv: H[s] lines are first touched by any
// reader only after the release, so they cannot be stale in L1/L2; h stores
// are agent-scope relaxed atomics drained by __syncthreads before the flag.
__global__ __launch_bounds__(512, 2) void k_hloop(
    const float* __restrict__ h0, const float* __restrict__ Whh,
    const float* __restrict__ Wih, const float* __restrict__ bih,
    const float* __restrict__ bhh, const float* __restrict__ emb,
    const int* __restrict__ target, const int* __restrict__ sosp,
    float* __restrict__ H, unsigned int* __restrict__ flags) {
  __shared__ float spad[20736];  // 82.9 KB: occupancy limiter (1 block/CU)
  float* g   = spad;             // 256: h-dot exchange
  float* Gls = spad + 256;       // 2 x 256: G pipeline (double buffer)
  int bi = blockIdx.x, d0 = bi*2;
  int tid = threadIdx.x;
  int w = tid>>6, lane = tid&63;
  float4 W0[8], W1[8], Wi0[8], Wi1[8];
#pragma unroll
  for (int j = 0; j < 8; j++) {
    int r = (j>>1)*DD + d0 + (j&1);
    const float* wp = Whh + (size_t)r*DD + lane*4;
    W0[j]  = *(const float4*)wp; W1[j]  = *(const float4*)(wp + 256);
    const float* ip = Wih + (size_t)r*DD + lane*4;
    Wi0[j] = *(const float4*)ip; Wi1[j] = *(const float4*)(ip + 256);
  }
  int jrole = lane & 7;
  int brow = (jrole>>1)*DD + d0 + (jrole&1);
  float biasj = bih[brow] + bhh[brow];
  int pb = tid>>1, pdd = tid&1;
  float creg = 0.f;
  if (tid < 64) creg = h0[pb*DD + d0 + pdd];

  // prologue: G[0] from emb[sos] (identical for all b)
  {
    int sos = sosp[0];
    const float* xp = emb + (size_t)sos*DD + lane*4;
    float4 x0 = *(const float4*)xp, x1 = *(const float4*)(xp + 256);
    float a0 = dot4(x0,Wi0[0]) + dot4(x1,Wi1[0]);
    float a1 = dot4(x0,Wi0[1]) + dot4(x1,Wi1[1]);
    float a2 = dot4(x0,Wi0[2]) + dot4(x1,Wi1[2]);
    float a3 = dot4(x0,Wi0[3]) + dot4(x1,Wi1[3]);
    float a4 = dot4(x0,Wi0[4]) + dot4(x1,Wi1[4]);
    float a5 = dot4(x0,Wi0[5]) + dot4(x1,Wi1[5]);
    float a6 = dot4(x0,Wi0[6]) + dot4(x1,Wi1[6]);
    float a7 = dot4(x0,Wi0[7]) + dot4(x1,Wi1[7]);
    float v = red8(a0,a1,a2,a3,a4,a5,a6,a7,lane);
    if (lane < 8) {
      float vb = v + biasj;
#pragma unroll
      for (int bb = 0; bb < 4; bb++) Gls[(w*4+bb)*8 + lane] = vb;
    }
  }
  __syncthreads();

  for (int s = 0; s < NSTEP; s++) {
    // pin both weight fragments in VGPRs for this iteration
#pragma unroll
    for (int j = 0; j < 8; j++) {
      asm volatile("" : "+v"(W0[j].x), "+v"(W0[j].y),
                        "+v"(W0[j].z), "+v"(W0[j].w),
                        "+v"(W1[j].x), "+v"(W1[j].y),
                        "+v"(W1[j].z), "+v"(W1[j].w));
      asm volatile("" : "+v"(Wi0[j].x), "+v"(Wi0[j].y),
                        "+v"(Wi0[j].z), "+v"(Wi0[j].w),
                        "+v"(Wi1[j].x), "+v"(Wi1[j].y),
                        "+v"(Wi1[j].z), "+v"(Wi1[j].w));
    }
    const float* hin = (s == 0) ? h0 : (H + (size_t)(s-1)*BB*DD);
#pragma unroll
    for (int bb = 0; bb < 4; bb++) {
      int b = w*4 + bb;
      const float* hp = hin + b*DD + lane*4;
      float4 h0v = *(const float4*)hp, h1v = *(const float4*)(hp + 256);
      float a0 = dot4(h0v,W0[0]) + dot4(h1v,W1[0]);
      float a1 = dot4(h0v,W0[1]) + dot4(h1v,W1[1]);
      float a2 = dot4(h0v,W0[2]) + dot4(h1v,W1[2]);
      float a3 = dot4(h0v,W0[3]) + dot4(h1v,W1[3]);
      float a4 = dot4(h0v,W0[4]) + dot4(h1v,W1[4]);
      float a5 = dot4(h0v,W0[5]) + dot4(h1v,W1[5]);
      float a6 = dot4(h0v,W0[6]) + dot4(h1v,W1[6]);
      float a7 = dot4(h0v,W0[7]) + dot4(h1v,W1[7]);
      float v = red8(a0,a1,a2,a3,a4,a5,a6,a7,lane);
      if (lane < 8) g[b*8 + lane] = v;
    }
    // prefetch next step's gathered emb rows (independent of this step's h)
    float4 xg0[4], xg1[4];
    if (s < NSTEP-1) {
#pragma unroll
      for (int bb = 0; bb < 4; bb++) {
        int tg = target[(s+1)*BB + w*4 + bb];
        const float* xp = emb + (size_t)tg*DD + lane*4;
        xg0[bb] = *(const float4*)xp; xg1[bb] = *(const float4*)(xp + 256);
      }
    }
    __syncthreads();
    if (tid < 64) {
      const float* Gs = Gls + (s&1)*256;
      float gi = g[pb*8 + 0 + pdd] + Gs[pb*8 + 0 + pdd];
      float gf = g[pb*8 + 2 + pdd] + Gs[pb*8 + 2 + pdd];
      float gg = g[pb*8 + 4 + pdd] + Gs[pb*8 + 4 + pdd];
      float go = g[pb*8 + 6 + pdd] + Gs[pb*8 + 6 + pdd];
      creg = sigm(gf)*creg + sigm(gi)*tanhf(gg);
      float hn = sigm(go)*tanhf(creg);
      __hip_atomic_store(H + (size_t)s*BB*DD + pb*DD + d0 + pdd, hn,
                         __ATOMIC_RELAXED, __HIP_MEMORY_SCOPE_AGENT);
    }
    if (s == NSTEP-1) break;   // end-of-kernel flush publishes the last step
    __syncthreads();           // vmcnt(0) drain: h stores visible before flag
    unsigned tgt = (unsigned)(s+1);
    if (tid == 0)
      __hip_atomic_store(&flags[bi], tgt,
                         __ATOMIC_RELAXED, __HIP_MEMORY_SCOPE_AGENT);
    // ---- G[s+1] dots: useful work that hides the barrier latency ----
    {
      float* Gd = Gls + ((s+1)&1)*256;
#pragma unroll
      for (int bb = 0; bb < 4; bb++) {
        float a0 = dot4(xg0[bb],Wi0[0]) + dot4(xg1[bb],Wi1[0]);
        float a1 = dot4(xg0[bb],Wi0[1]) + dot4(xg1[bb],Wi1[1]);
        float a2 = dot4(xg0[bb],Wi0[2]) + dot4(xg1[bb],Wi1[2]);
        float a3 = dot4(xg0[bb],Wi0[3]) + dot4(xg1[bb],Wi1[3]);
        float a4 = dot4(xg0[bb],Wi0[4]) + dot4(xg1[bb],Wi1[4]);
        float a5 = dot4(xg0[bb],Wi0[5]) + dot4(xg1[bb],Wi1[5]);
        float a6 = dot4(xg0[bb],Wi0[6]) + dot4(xg1[bb],Wi1[6]);
        float a7 = dot4(xg0[bb],Wi0[7]) + dot4(xg1[bb],Wi1[7]);
        float v = red8(a0,a1,a2,a3,a4,a5,a6,a7,lane);
        if (lane < 8) Gd[(w*4+bb)*8 + lane] = v + biasj;
      }
    }
    if (bi == 0 && tid < 64) {
      // gatherer wave: poll 4 flags/lane; reconverges when all lanes done
      const unsigned int* fp = flags + tid*4;
      for (;;) {
        unsigned f0 = __hip_atomic_load(fp+0, __ATOMIC_RELAXED,
                                        __HIP_MEMORY_SCOPE_AGENT);
        unsigned f1 = __hip_atomic_load(fp+1, __ATOMIC_RELAXED,
                                        __HIP_MEMORY_SCOPE_AGENT);
        unsigned f2 = __hip_atomic_load(fp+2, __ATOMIC_RELAXED,
                                        __HIP_MEMORY_SCOPE_AGENT);
        unsigned f3 = __hip_atomic_load(fp+3, __ATOMIC_RELAXED,
                                        __HIP_MEMORY_SCOPE_AGENT);
        if (f0 >= tgt && f1 >= tgt && f2 >= tgt && f3 >= tgt) break;
        __builtin_amdgcn_s_sleep(1);
      }
      if (tid == 0)
        __hip_atomic_store(&flags[256], tgt,
                           __ATOMIC_RELAXED, __HIP_MEMORY_SCOPE_AGENT);
    }
    if (tid == 0) {
      while (__hip_atomic_load(&flags[256], __ATOMIC_RELAXED,
                               __HIP_MEMORY_SCOPE_AGENT) < tgt)
        __builtin_amdgcn_s_sleep(1);
    }
    __syncthreads();
  }
}

// ---------------- Q[m,r] = H[m].Watt[r], all steps -------------------------
__global__ __launch_bounds__(256) void k_qallw(
    const float* __restrict__ H, const float* __restrict__ Watt,
    float* __restrict__ Q) {
  int nt = blockIdx.x, mg = blockIdx.y;
  int w = threadIdx.x>>6, lane = threadIdx.x&63;
  int m0 = mg*32 + w*8;
  float4 x0[8], x1[8];
#pragma unroll
  for (int j = 0; j < 8; j++) {
    const float* xp = H + (size_t)(m0 + j)*DD + lane*4;
    x0[j] = *(const float4*)xp; x1[j] = *(const float4*)(xp + 256);
  }
  int r0 = nt*16;
#pragma unroll 2
  for (int i = 0; i < 16; i++) {
    int r = r0 + i;
    const float* wp = Watt + (size_t)r*DD + lane*4;
    float4 w0 = *(const float4*)wp, w1 = *(const float4*)(wp + 256);
    float a0 = dot4(w0,x0[0]) + dot4(w1,x1[0]);
    float a1 = dot4(w0,x0[1]) + dot4(w1,x1[1]);
    float a2 = dot4(w0,x0[2]) + dot4(w1,x1[2]);
    float a3 = dot4(w0,x0[3]) + dot4(w1,x1[3]);
    float a4 = dot4(w0,x0[4]) + dot4(w1,x1[4]);
    float a5 = dot4(w0,x0[5]) + dot4(w1,x1[5]);
    float a6 = dot4(w0,x0[6]) + dot4(w1,x1[6]);
    float a7 = dot4(w0,x0[7]) + dot4(w1,x1[7]);
    float v = red8(a0,a1,a2,a3,a4,a5,a6,a7,lane);
    if (lane < 8) Q[(size_t)(m0 + lane)*DD + r] = v;
  }
}

// ---------------- S[s,b,n] = enc[b,n,:].Q[s*32+b,:] ------------------------
__global__ __launch_bounds__(256) void k_scores3(
    const float* __restrict__ enc, const float* __restrict__ Q,
    float* __restrict__ S) {
  int nt = blockIdx.x, b = blockIdx.y;
  int w = threadIdx.x>>6, lane = threadIdx.x&63;
  int s0 = w*8;
  float4 q0[8], q1[8];
#pragma unroll
  for (int j = 0; j < 8; j++) {
    const float* qp = Q + (size_t)((s0 + j)*BB + b)*DD + lane*4;
    q0[j] = *(const float4*)qp; q1[j] = *(const float4*)(qp + 256);
  }
  int n0 = nt*32;
  int sl = s0 + (lane & 7);
#pragma unroll 2
  for (int i = 0; i < 32; i++) {
    int n = n0 + i;
    const float* ep = enc + ((size_t)(b*NN + n))*DD + lane*4;
    float4 e0 = *(const float4*)ep, e1 = *(const float4*)(ep + 256);
    float a0 = dot4(e0,q0[0]) + dot4(e1,q1[0]);
    float a1 = dot4(e0,q0[1]) + dot4(e1,q1[1]);
    float a2 = dot4(e0,q0[2]) + dot4(e1,q1[2]);
    float a3 = dot4(e0,q0[3]) + dot4(e1,q1[3]);
    float a4 = dot4(e0,q0[4]) + dot4(e1,q1[4]);
    float a5 = dot4(e0,q0[5]) + dot4(e1,q1[5]);
    float a6 = dot4(e0,q0[6]) + dot4(e1,q1[6]);
    float a7 = dot4(e0,q0[7]) + dot4(e1,q1[7]);
    float v = red8(a0,a1,a2,a3,a4,a5,a6,a7,lane);
    if (lane < 8 && sl < NSTEP) S[((size_t)sl*BB + b)*NN + n] = v;
  }
}

// ---------------- zero row + masked softmax + threshold + scatter + eos ----
__global__ __launch_bounds__(256) void k_scatter2(
    const float* __restrict__ S, const int* __restrict__ pmask,
    const int* __restrict__ tok, const float* __restrict__ thr,
    const int* __restrict__ eosp, float* __restrict__ out) {
  __shared__ float red[256];
  __shared__ float ex[NN];
  int s = blockIdx.x, b = blockIdx.y, tid = threadIdx.x;
  float* orow = out + ((size_t)(s+1)*BB + b)*VV;
  float4 z = {0.f,0.f,0.f,0.f};
  float4* orow4 = (float4*)orow;
  for (int i = tid; i < VV/4; i += 256) orow4[i] = z;
  const float* sr = S + ((size_t)s*BB + b)*NN;
  const int* pm = pmask + b*NN;
  float m = -3.4e38f;
  for (int n = tid; n < NN; n += 256) if (pm[n]) m = fmaxf(m, sr[n]);
  red[tid] = m; __syncthreads();
  for (int st = 128; st; st >>= 1) {
    if (tid < st) red[tid] = fmaxf(red[tid], red[tid+st]);
    __syncthreads();
  }
  float smax = red[0]; __syncthreads();
  float sum = 0.f;
  for (int n = tid; n < NN; n += 256) {
    float e = pm[n] ? expf(sr[n] - smax) : 0.f;
    ex[n] = e; sum += e;
  }
  red[tid] = sum; __syncthreads();
  for (int st = 128; st; st >>= 1) {
    if (tid < st) red[tid] += red[tid+st];
    __syncthreads();
  }
  float inv = 1.0f/red[0];
  float th = thr[b];
  float keep = 0.f;
  for (int n = tid; n < NN; n += 256) {
    float p = ex[n]*inv;
    if (p >= th) { atomicAdd(orow + tok[b*NN + n], p); keep += p; }
  }
  __syncthreads();
  red[tid] = keep; __syncthreads();
  for (int st = 128; st; st >>= 1) {
    if (tid < st) red[tid] += red[tid+st];
    __syncthreads();
  }
  if (tid == 0) orow[eosp[0]] = 1.0f - red[0];
}

extern "C" void kernel_launch(void* const* d_in, const int* in_sizes, int n_in,
                              void* d_out, int out_size, void* d_ws, size_t ws_size,
                              hipStream_t stream) {
  const float* enc   = (const float*)d_in[0];
  const float* emb   = (const float*)d_in[1];
  const float* Wih   = (const float*)d_in[2];
  const float* Whh   = (const float*)d_in[3];
  const float* bih   = (const float*)d_in[4];
  const float* bhh   = (const float*)d_in[5];
  const float* Watt  = (const float*)d_in[6];
  const int*   pad   = (const int*)d_in[7];
  const int*   pmask = (const int*)d_in[8];
  const int*   tok   = (const int*)d_in[9];
  const int*   target= (const int*)d_in[10];
  const int*   sosp  = (const int*)d_in[11];
  const int*   eosp  = (const int*)d_in[12];
  float* out = (float*)d_out;

  // workspace layout (floats), ~20.5 MB. hpart aliases G0-space (pre-use only).
  float* w    = (float*)d_ws;
  float* c    = w;                          // 32*512 (legacy; unused by hloop)
  float* h0   = c    + BB*DD;               // 32*512
  float* H    = h0   + BB*DD;               // 31*32*512
  float* Q    = H    + NSTEP*BB*DD;         // padded: 32*32*512
  float* S    = Q    + 32*BB*DD;            // 31*32*2048
  float* G0   = S    + (size_t)NSTEP*BB*NN; // 992*2048 (now scratch only)
  float* cntp = G0   + (size_t)992*2048;    // 32
  float* thr  = cntp + 32;                  // 32
  unsigned int* flags = (unsigned int*)(thr + 32); // 256 flags + release word
  float* hpart = G0;                        // 32*64*512 (alias)

  k_cnt<<<32, 256, 0, stream>>>(pad, pmask, sosp, cntp, thr, out, flags);
  k_meanpart<<<dim3(32,64), 128, 0, stream>>>(enc, pad, hpart);
  k_meanfin<<<32, 128, 0, stream>>>(hpart, cntp, h0, c);

  k_hloop<<<256, 512, 0, stream>>>(h0, Whh, Wih, bih, bhh, emb, target, sosp,
                                   H, flags);

  k_qallw<<<dim3(32,31), 256, 0, stream>>>(H, Watt, Q);
  k_scores3<<<dim3(64,32), 256, 0, stream>>>(enc, Q, S);
  k_scatter2<<<dim3(NSTEP,32), 256, 0, stream>>>(S, pmask, tok, thr, eosp, out);
}

// Round 6
// 598.724 us; speedup vs baseline: 1.8777x; 1.0063x over previous
//
#include <hip/hip_runtime.h>
#include <math.h>

#define BB 32
#define NN 2048
#define DD 512
#define VV 32000
#define NSTEP 31

__device__ inline float sigm(float x){ return 1.0f/(1.0f+expf(-x)); }
__device__ inline float dot4(float4 a, float4 b){
  return a.x*b.x + a.y*b.y + a.z*b.z + a.w*b.w;
}

// Merged 8-way wave reduction: returns, in every lane, the full 64-lane sum
// of a_{lane&7}.
__device__ inline float red8(float a0,float a1,float a2,float a3,
                             float a4,float a5,float a6,float a7,int lane){
  float m01 = ((lane&1)? a1:a0) + __shfl_xor(((lane&1)? a0:a1),1,64);
  float m23 = ((lane&1)? a3:a2) + __shfl_xor(((lane&1)? a2:a3),1,64);
  float m45 = ((lane&1)? a5:a4) + __shfl_xor(((lane&1)? a4:a5),1,64);
  float m67 = ((lane&1)? a7:a6) + __shfl_xor(((lane&1)? a6:a7),1,64);
  float m03 = ((lane&2)? m23:m01) + __shfl_xor(((lane&2)? m01:m23),2,64);
  float m47 = ((lane&2)? m67:m45) + __shfl_xor(((lane&2)? m45:m67),2,64);
  float m   = ((lane&4)? m47:m03) + __shfl_xor(((lane&4)? m03:m47),4,64);
  m += __shfl_xor(m,8,64); m += __shfl_xor(m,16,64); m += __shfl_xor(m,32,64);
  return m;
}

// Coalesced cache-bypassing flag read: one global_load_dwordx4 sc0 sc1 per
// lane (wave-coalesced into 16 line transactions for 256 flags) -- fresh
// from the coherence point, unlike plain loads; unlike per-dword atomic
// loads it coalesces (round-3's storm was 256 uncoalesced atomics/block).
__device__ inline uint4 fresh_load4(const unsigned int* p){
  uint4 r;
  asm volatile("global_load_dwordx4 %0, %1, off sc0 sc1\n\t"
               "s_waitcnt vmcnt(0)"
               : "=&v"(r) : "v"(p) : "memory");
  return r;
}

// ---------------- counts, threshold; zero step-0 rows + sos one-hot --------
__global__ __launch_bounds__(256) void k_cnt(
    const int* __restrict__ pad, const int* __restrict__ pmask,
    const int* __restrict__ sosp,
    float* __restrict__ cntp, float* __restrict__ thr, float* __restrict__ out,
    unsigned int* __restrict__ flags) {
  __shared__ int r1[256], r2[256];
  int b = blockIdx.x, tid = threadIdx.x;
  if (b == 0 && tid < 256)
    __hip_atomic_store(&flags[tid], 0u, __ATOMIC_RELAXED,
                       __HIP_MEMORY_SCOPE_AGENT);
  float4* orow4 = (float4*)(out + (size_t)b*VV);
  float4 z = {0.f,0.f,0.f,0.f};
  for (int i = tid; i < VV/4; i += 256) orow4[i] = z;
  int cp = 0, cq = 0;
  for (int n = tid; n < NN; n += 256) { cp += pad[b*NN+n]; cq += pmask[b*NN+n]; }
  r1[tid] = cp; r2[tid] = cq; __syncthreads();
  for (int st = 128; st; st >>= 1) {
    if (tid < st) { r1[tid] += r1[tid+st]; r2[tid] += r2[tid+st]; }
    __syncthreads();
  }
  if (tid == 0) {
    cntp[b] = (float)r1[0];
    thr[b]  = 1.0f/(float)r2[0];
    out[(size_t)b*VV + sosp[0]] = 1.0f;
  }
}

// ---------------- h0 mean: partial sums (branch-free) ----------------------
__global__ __launch_bounds__(128) void k_meanpart(
    const float* __restrict__ enc, const int* __restrict__ pad,
    float* __restrict__ hpart) {
  int b = blockIdx.x, ch = blockIdx.y, kq = threadIdx.x;
  int n0 = ch*32;
  float4 acc = {0.f,0.f,0.f,0.f};
#pragma unroll 8
  for (int r = 0; r < 32; r++) {
    int n = n0 + r;
    float msk = (float)pad[b*NN + n];
    float4 v = *(const float4*)(enc + ((size_t)(b*NN + n))*DD + kq*4);
    acc.x += msk*v.x; acc.y += msk*v.y; acc.z += msk*v.z; acc.w += msk*v.w;
  }
  *(float4*)(hpart + ((size_t)(b*64 + ch))*DD + kq*4) = acc;
}

__global__ __launch_bounds__(128) void k_meanfin(
    const float* __restrict__ hpart, const float* __restrict__ cntp,
    float* __restrict__ h0, float* __restrict__ c) {
  int b = blockIdx.x, kq = threadIdx.x;
  float4 acc = {0.f,0.f,0.f,0.f};
  for (int ch = 0; ch < 64; ch++) {
    float4 v = *(const float4*)(hpart + ((size_t)(b*64 + ch))*DD + kq*4);
    acc.x += v.x; acc.y += v.y; acc.z += v.z; acc.w += v.w;
  }
  float ic = 1.0f/cntp[b];
  acc.x *= ic; acc.y *= ic; acc.z *= ic; acc.w *= ic;
  *(float4*)(h0 + b*DD + kq*4) = acc;
  *(float4*)(c  + b*DD + kq*4) = acc;
}

// ---------------- fused 31-step LSTM recurrence + G0 + Q pipelines ---------
// 256 blocks x 512 threads; 83 KB LDS forces 1 block/CU. Block bi owns
// d-cols {2bi,2bi+1}: 8 Whh rows + 8 Wih rows + 2 Watt rows pinned in VGPRs.
//
// Per-step barrier, v5 (single-hop): arrival = per-block flag store; wait =
// every block's wave0 polls ALL 256 flags with ONE coalesced fresh dwordx4
// load per round (no gather, no release hop).
// Barrier-wait window is filled with useful work:
//   - G[s+1] input-gate dots (emb gather prefetched pre-sync)   [round 5]
//   - Q[s-1] = H[s-1].Watt dots, reusing the h vectors already loaded into
//     registers for this step's h-dots -> k_qallw kernel deleted. Q[30] is
//     computed in an epilogue after the final barrier (which also publishes
//     H[30] for it).
// H[s] lines are first-touched by readers only after the flag observation
// (and the inter-iteration workspace poison fully flushes L2s), so no
// per-step acquire/L2-invalidate is needed (round-5-verified).
__global__ __launch_bounds__(512, 2) void k_hloop(
    const float* __restrict__ h0, const float* __restrict__ Whh,
    const float* __restrict__ Wih, const float* __restrict__ bih,
    const float* __restrict__ bhh, const float* __restrict__ emb,
    const float* __restrict__ Watt, const int* __restrict__ target,
    const int* __restrict__ sosp, float* __restrict__ H,
    float* __restrict__ Q, unsigned int* __restrict__ flags) {
  __shared__ float spad[20736];  // 82.9 KB: occupancy limiter (1 block/CU)
  float* g   = spad;             // 256: h-dot exchange
  float* Gls = spad + 256;       // 2 x 256: G pipeline (double buffer)
  int bi = blockIdx.x, d0 = bi*2;
  int tid = threadIdx.x;
  int w = tid>>6, lane = tid&63;
  float4 W0[8], W1[8], Wi0[8], Wi1[8], Wa0[2], Wa1[2];
#pragma unroll
  for (int j = 0; j < 8; j++) {
    int r = (j>>1)*DD + d0 + (j&1);
    const float* wp = Whh + (size_t)r*DD + lane*4;
    W0[j]  = *(const float4*)wp; W1[j]  = *(const float4*)(wp + 256);
    const float* ip = Wih + (size_t)r*DD + lane*4;
    Wi0[j] = *(const float4*)ip; Wi1[j] = *(const float4*)(ip + 256);
  }
#pragma unroll
  for (int e = 0; e < 2; e++) {
    const float* ap = Watt + (size_t)(d0+e)*DD + lane*4;
    Wa0[e] = *(const float4*)ap; Wa1[e] = *(const float4*)(ap + 256);
  }
  int jrole = lane & 7;
  int brow = (jrole>>1)*DD + d0 + (jrole&1);
  float biasj = bih[brow] + bhh[brow];
  int pb = tid>>1, pdd = tid&1;
  float creg = 0.f;
  if (tid < 64) creg = h0[pb*DD + d0 + pdd];

  // prologue: G[0] from emb[sos] (identical for all b)
  {
    int sos = sosp[0];
    const float* xp = emb + (size_t)sos*DD + lane*4;
    float4 x0 = *(const float4*)xp, x1 = *(const float4*)(xp + 256);
    float a0 = dot4(x0,Wi0[0]) + dot4(x1,Wi1[0]);
    float a1 = dot4(x0,Wi0[1]) + dot4(x1,Wi1[1]);
    float a2 = dot4(x0,Wi0[2]) + dot4(x1,Wi1[2]);
    float a3 = dot4(x0,Wi0[3]) + dot4(x1,Wi1[3]);
    float a4 = dot4(x0,Wi0[4]) + dot4(x1,Wi1[4]);
    float a5 = dot4(x0,Wi0[5]) + dot4(x1,Wi1[5]);
    float a6 = dot4(x0,Wi0[6]) + dot4(x1,Wi1[6]);
    float a7 = dot4(x0,Wi0[7]) + dot4(x1,Wi1[7]);
    float v = red8(a0,a1,a2,a3,a4,a5,a6,a7,lane);
    if (lane < 8) {
      float vb = v + biasj;
#pragma unroll
      for (int bb = 0; bb < 4; bb++) Gls[(w*4+bb)*8 + lane] = vb;
    }
  }
  __syncthreads();

  float4 h0s[4], h1s[4];
  for (int s = 0; s < NSTEP; s++) {
    // pin all weight fragments in VGPRs for this iteration
#pragma unroll
    for (int j = 0; j < 8; j++) {
      asm volatile("" : "+v"(W0[j].x), "+v"(W0[j].y),
                        "+v"(W0[j].z), "+v"(W0[j].w),
                        "+v"(W1[j].x), "+v"(W1[j].y),
                        "+v"(W1[j].z), "+v"(W1[j].w));
      asm volatile("" : "+v"(Wi0[j].x), "+v"(Wi0[j].y),
                        "+v"(Wi0[j].z), "+v"(Wi0[j].w),
                        "+v"(Wi1[j].x), "+v"(Wi1[j].y),
                        "+v"(Wi1[j].z), "+v"(Wi1[j].w));
    }
#pragma unroll
    for (int e = 0; e < 2; e++) {
      asm volatile("" : "+v"(Wa0[e].x), "+v"(Wa0[e].y),
                        "+v"(Wa0[e].z), "+v"(Wa0[e].w),
                        "+v"(Wa1[e].x), "+v"(Wa1[e].y),
                        "+v"(Wa1[e].z), "+v"(Wa1[e].w));
    }
    const float* hin = (s == 0) ? h0 : (H + (size_t)(s-1)*BB*DD);
#pragma unroll
    for (int bb = 0; bb < 4; bb++) {
      int b = w*4 + bb;
      const float* hp = hin + b*DD + lane*4;
      float4 h0v = *(const float4*)hp, h1v = *(const float4*)(hp + 256);
      h0s[bb] = h0v; h1s[bb] = h1v;
      float a0 = dot4(h0v,W0[0]) + dot4(h1v,W1[0]);
      float a1 = dot4(h0v,W0[1]) + dot4(h1v,W1[1]);
      float a2 = dot4(h0v,W0[2]) + dot4(h1v,W1[2]);
      float a3 = dot4(h0v,W0[3]) + dot4(h1v,W1[3]);
      float a4 = dot4(h0v,W0[4]) + dot4(h1v,W1[4]);
      float a5 = dot4(h0v,W0[5]) + dot4(h1v,W1[5]);
      float a6 = dot4(h0v,W0[6]) + dot4(h1v,W1[6]);
      float a7 = dot4(h0v,W0[7]) + dot4(h1v,W1[7]);
      float v = red8(a0,a1,a2,a3,a4,a5,a6,a7,lane);
      if (lane < 8) g[b*8 + lane] = v;
    }
    // prefetch next step's gathered emb rows (independent of this step's h)
    float4 xg0[4], xg1[4];
    if (s < NSTEP-1) {
#pragma unroll
      for (int bb = 0; bb < 4; bb++) {
        int tg = target[(s+1)*BB + w*4 + bb];
        const float* xp = emb + (size_t)tg*DD + lane*4;
        xg0[bb] = *(const float4*)xp; xg1[bb] = *(const float4*)(xp + 256);
      }
    }
    __syncthreads();
    if (tid < 64) {
      const float* Gs = Gls + (s&1)*256;
      float gi = g[pb*8 + 0 + pdd] + Gs[pb*8 + 0 + pdd];
      float gf = g[pb*8 + 2 + pdd] + Gs[pb*8 + 2 + pdd];
      float gg = g[pb*8 + 4 + pdd] + Gs[pb*8 + 4 + pdd];
      float go = g[pb*8 + 6 + pdd] + Gs[pb*8 + 6 + pdd];
      creg = sigm(gf)*creg + sigm(gi)*tanhf(gg);
      float hn = sigm(go)*tanhf(creg);
      __hip_atomic_store(H + (size_t)s*BB*DD + pb*DD + d0 + pdd, hn,
                         __ATOMIC_RELAXED, __HIP_MEMORY_SCOPE_AGENT);
    }
    __syncthreads();           // vmcnt(0) drain: h stores visible before flag
    unsigned tgt = (unsigned)(s+1);
    if (tid == 0)
      __hip_atomic_store(&flags[bi], tgt,
                         __ATOMIC_RELAXED, __HIP_MEMORY_SCOPE_AGENT);
    // ---- barrier-wait window: useful work ----
    if (s < NSTEP-1) {         // G[s+1] dots
      float* Gd = Gls + ((s+1)&1)*256;
#pragma unroll
      for (int bb = 0; bb < 4; bb++) {
        float a0 = dot4(xg0[bb],Wi0[0]) + dot4(xg1[bb],Wi1[0]);
        float a1 = dot4(xg0[bb],Wi0[1]) + dot4(xg1[bb],Wi1[1]);
        float a2 = dot4(xg0[bb],Wi0[2]) + dot4(xg1[bb],Wi1[2]);
        float a3 = dot4(xg0[bb],Wi0[3]) + dot4(xg1[bb],Wi1[3]);
        float a4 = dot4(xg0[bb],Wi0[4]) + dot4(xg1[bb],Wi1[4]);
        float a5 = dot4(xg0[bb],Wi0[5]) + dot4(xg1[bb],Wi1[5]);
        float a6 = dot4(xg0[bb],Wi0[6]) + dot4(xg1[bb],Wi1[6]);
        float a7 = dot4(xg0[bb],Wi0[7]) + dot4(xg1[bb],Wi1[7]);
        float v = red8(a0,a1,a2,a3,a4,a5,a6,a7,lane);
        if (lane < 8) Gd[(w*4+bb)*8 + lane] = v + biasj;
      }
    }
    if (s > 0) {               // Q[s-1] dots from this step's hin registers
#pragma unroll
      for (int bb = 0; bb < 4; bb++) {
        float q0 = dot4(h0s[bb],Wa0[0]) + dot4(h1s[bb],Wa1[0]);
        float q1 = dot4(h0s[bb],Wa0[1]) + dot4(h1s[bb],Wa1[1]);
        float v = red8(q0,q1,0.f,0.f,0.f,0.f,0.f,0.f,lane);
        if (lane < 2)
          Q[((size_t)(s-1)*BB + w*4 + bb)*DD + d0 + lane] = v;
      }
    }
    // ---- single-hop poll: wave0 reads all 256 flags, coalesced + fresh ----
    if (tid < 64) {
      const unsigned int* fp = flags + tid*4;
      for (;;) {
        uint4 f = fresh_load4(fp);
        bool ok = f.x >= tgt && f.y >= tgt && f.z >= tgt && f.w >= tgt;
        if (__all(ok)) break;
        __builtin_amdgcn_s_sleep(1);
      }
    }
    __syncthreads();
  }

  // epilogue: Q[30] from H[30] (published by the final barrier above)
#pragma unroll
  for (int bb = 0; bb < 4; bb++) {
    int b = w*4 + bb;
    const float* hp = H + (size_t)(NSTEP-1)*BB*DD + b*DD + lane*4;
    float4 h0v = *(const float4*)hp, h1v = *(const float4*)(hp + 256);
    float q0 = dot4(h0v,Wa0[0]) + dot4(h1v,Wa1[0]);
    float q1 = dot4(h0v,Wa0[1]) + dot4(h1v,Wa1[1]);
    float v = red8(q0,q1,0.f,0.f,0.f,0.f,0.f,0.f,lane);
    if (lane < 2)
      Q[((size_t)(NSTEP-1)*BB + b)*DD + d0 + lane] = v;
  }
}

// ---------------- S[s,b,n] = enc[b,n,:].Q[s*32+b,:] ------------------------
__global__ __launch_bounds__(256) void k_scores3(
    const float* __restrict__ enc, const float* __restrict__ Q,
    float* __restrict__ S) {
  int nt = blockIdx.x, b = blockIdx.y;
  int w = threadIdx.x>>6, lane = threadIdx.x&63;
  int s0 = w*8;
  float4 q0[8], q1[8];
#pragma unroll
  for (int j = 0; j < 8; j++) {
    const float* qp = Q + (size_t)((s0 + j)*BB + b)*DD + lane*4;
    q0[j] = *(const float4*)qp; q1[j] = *(const float4*)(qp + 256);
  }
  int n0 = nt*32;
  int sl = s0 + (lane & 7);
#pragma unroll 2
  for (int i = 0; i < 32; i++) {
    int n = n0 + i;
    const float* ep = enc + ((size_t)(b*NN + n))*DD + lane*4;
    float4 e0 = *(const float4*)ep, e1 = *(const float4*)(ep + 256);
    float a0 = dot4(e0,q0[0]) + dot4(e1,q1[0]);
    float a1 = dot4(e0,q0[1]) + dot4(e1,q1[1]);
    float a2 = dot4(e0,q0[2]) + dot4(e1,q1[2]);
    float a3 = dot4(e0,q0[3]) + dot4(e1,q1[3]);
    float a4 = dot4(e0,q0[4]) + dot4(e1,q1[4]);
    float a5 = dot4(e0,q0[5]) + dot4(e1,q1[5]);
    float a6 = dot4(e0,q0[6]) + dot4(e1,q1[6]);
    float a7 = dot4(e0,q0[7]) + dot4(e1,q1[7]);
    float v = red8(a0,a1,a2,a3,a4,a5,a6,a7,lane);
    if (lane < 8 && sl < NSTEP) S[((size_t)sl*BB + b)*NN + n] = v;
  }
}

// ---------------- zero row + masked softmax + threshold + scatter + eos ----
__global__ __launch_bounds__(256) void k_scatter2(
    const float* __restrict__ S, const int* __restrict__ pmask,
    const int* __restrict__ tok, const float* __restrict__ thr,
    const int* __restrict__ eosp, float* __restrict__ out) {
  __shared__ float red[256];
  __shared__ float ex[NN];
  int s = blockIdx.x, b = blockIdx.y, tid = threadIdx.x;
  float* orow = out + ((size_t)(s+1)*BB + b)*VV;
  float4 z = {0.f,0.f,0.f,0.f};
  float4* orow4 = (float4*)orow;
  for (int i = tid; i < VV/4; i += 256) orow4[i] = z;
  const float* sr = S + ((size_t)s*BB + b)*NN;
  const int* pm = pmask + b*NN;
  float m = -3.4e38f;
  for (int n = tid; n < NN; n += 256) if (pm[n]) m = fmaxf(m, sr[n]);
  red[tid] = m; __syncthreads();
  for (int st = 128; st; st >>= 1) {
    if (tid < st) red[tid] = fmaxf(red[tid], red[tid+st]);
    __syncthreads();
  }
  float smax = red[0]; __syncthreads();
  float sum = 0.f;
  for (int n = tid; n < NN; n += 256) {
    float e = pm[n] ? expf(sr[n] - smax) : 0.f;
    ex[n] = e; sum += e;
  }
  red[tid] = sum; __syncthreads();
  for (int st = 128; st; st >>= 1) {
    if (tid < st) red[tid] += red[tid+st];
    __syncthreads();
  }
  float inv = 1.0f/red[0];
  float th = thr[b];
  float keep = 0.f;
  for (int n = tid; n < NN; n += 256) {
    float p = ex[n]*inv;
    if (p >= th) { atomicAdd(orow + tok[b*NN + n], p); keep += p; }
  }
  __syncthreads();
  red[tid] = keep; __syncthreads();
  for (int st = 128; st; st >>= 1) {
    if (tid < st) red[tid] += red[tid+st];
    __syncthreads();
  }
  if (tid == 0) orow[eosp[0]] = 1.0f - red[0];
}

extern "C" void kernel_launch(void* const* d_in, const int* in_sizes, int n_in,
                              void* d_out, int out_size, void* d_ws, size_t ws_size,
                              hipStream_t stream) {
  const float* enc   = (const float*)d_in[0];
  const float* emb   = (const float*)d_in[1];
  const float* Wih   = (const float*)d_in[2];
  const float* Whh   = (const float*)d_in[3];
  const float* bih   = (const float*)d_in[4];
  const float* bhh   = (const float*)d_in[5];
  const float* Watt  = (const float*)d_in[6];
  const int*   pad   = (const int*)d_in[7];
  const int*   pmask = (const int*)d_in[8];
  const int*   tok   = (const int*)d_in[9];
  const int*   target= (const int*)d_in[10];
  const int*   sosp  = (const int*)d_in[11];
  const int*   eosp  = (const int*)d_in[12];
  float* out = (float*)d_out;

  // workspace layout (floats), ~20.5 MB. hpart aliases G0-space (pre-use only).
  float* w    = (float*)d_ws;
  float* c    = w;                          // 32*512 (legacy; unused by hloop)
  float* h0   = c    + BB*DD;               // 32*512
  float* H    = h0   + BB*DD;               // 31*32*512
  float* Q    = H    + NSTEP*BB*DD;         // padded: 32*32*512
  float* S    = Q    + 32*BB*DD;            // 31*32*2048
  float* G0   = S    + (size_t)NSTEP*BB*NN; // 992*2048 (scratch only)
  float* cntp = G0   + (size_t)992*2048;    // 32
  float* thr  = cntp + 32;                  // 32
  unsigned int* flags = (unsigned int*)(thr + 32); // 256 step flags
  float* hpart = G0;                        // 32*64*512 (alias)

  k_cnt<<<32, 256, 0, stream>>>(pad, pmask, sosp, cntp, thr, out, flags);
  k_meanpart<<<dim3(32,64), 128, 0, stream>>>(enc, pad, hpart);
  k_meanfin<<<32, 128, 0, stream>>>(hpart, cntp, h0, c);

  k_hloop<<<256, 512, 0, stream>>>(h0, Whh, Wih, bih, bhh, emb, Watt, target,
                                   sosp, H, Q, flags);

  k_scores3<<<dim3(64,32), 256, 0, stream>>>(enc, Q, S);
  k_scatter2<<<dim3(NSTEP,32), 256, 0, stream>>>(S, pmask, tok, thr, eosp, out);
}